// Round 1
// baseline (1438.772 us; speedup 1.0000x reference)
//
#include <hip/hip_runtime.h>
#include <hip/hip_bf16.h>

// ---------------------------------------------------------------------------
// GraphSAGE (3x SAGEConv mean + linear head), fp32.
// Pipeline per launch:
//   zero(cnt); count(dst); inv = 1/max(cnt,1)
//   zero(agg16); scatter16(x) ; layer16  -> hA   (16 -> 128, relu)
//   zero(agg)  ; scatter128(hA); layer128 -> hB  (128 -> 128, relu)
//   zero(agg)  ; scatter128(hB); layer128 -> hA  (128 -> 128, relu)
//   head(hA) -> out                               (128 -> 4)
// ---------------------------------------------------------------------------

__global__ void zero_kernel(float4* __restrict__ p, int n4) {
    int i = blockIdx.x * 256 + threadIdx.x;
    if (i < n4) p[i] = make_float4(0.f, 0.f, 0.f, 0.f);
}

__global__ void count_kernel(const int* __restrict__ dst, float* __restrict__ cnt, int E) {
    int e = blockIdx.x * 256 + threadIdx.x;
    if (e < E) atomicAdd(&cnt[dst[e]], 1.0f);
}

__global__ void inv_kernel(float* __restrict__ cnt, int n) {
    int i = blockIdx.x * 256 + threadIdx.x;
    if (i < n) cnt[i] = 1.0f / fmaxf(cnt[i], 1.0f);
}

// scatter x[src] rows (16 feats) into agg16[dst]
__global__ void scatter16_kernel(const float* __restrict__ x,
                                 const int* __restrict__ src,
                                 const int* __restrict__ dst,
                                 float* __restrict__ agg, int total) {
    int idx = blockIdx.x * 256 + threadIdx.x;
    if (idx >= total) return;
    int e = idx >> 4;
    int f = idx & 15;
    atomicAdd(&agg[dst[e] * 16 + f], x[src[e] * 16 + f]);
}

// scatter h[src] rows (128 feats) into agg[dst]
__global__ void scatter128_kernel(const float* __restrict__ h,
                                  const int* __restrict__ src,
                                  const int* __restrict__ dst,
                                  float* __restrict__ agg, int total) {
    int idx = blockIdx.x * 256 + threadIdx.x;
    if (idx >= total) return;
    int e = idx >> 7;
    int f = idx & 127;
    atomicAdd(&agg[dst[e] * 128 + f], h[src[e] * 128 + f]);
}

// layer 1: 16 -> 128.  h[i,o] = relu(b[o] + sum_f agg16[i,f]*inv[i]*Wl[o,f] + x[i,f]*Wr[o,f])
// 2 nodes per 256-thread block; Wl/Wr are 8KB each (L1-resident).
__global__ __launch_bounds__(256) void layer16_kernel(
    const float* __restrict__ agg16, const float* __restrict__ x,
    const float* __restrict__ inv, const float* __restrict__ Wl,
    const float* __restrict__ Wr, const float* __restrict__ bias,
    float* __restrict__ hout, int n) {
    int t = threadIdx.x;
    int o = t & 127;
    int node = blockIdx.x * 2 + (t >> 7);
    if (node >= n) return;
    float iv = inv[node];
    const float* wlr = Wl + o * 16;
    const float* wrr = Wr + o * 16;
    const float* ar  = agg16 + node * 16;
    const float* xr  = x + node * 16;
    float acc = bias[o];
    #pragma unroll
    for (int f = 0; f < 16; ++f) {
        acc = fmaf(ar[f] * iv, wlr[f], acc);
        acc = fmaf(xr[f],      wrr[f], acc);
    }
    hout[node * 128 + o] = fmaxf(acc, 0.0f);
}

// layer 2/3: 128 -> 128, tiled.  32 nodes/block, 256 threads.
// W chunks staged transposed in LDS (wl_s[k][o]) for conflict-free compute reads;
// feature reads are wave-wide broadcasts (all lanes of a wave share the node set).
__global__ __launch_bounds__(256) void layer128_kernel(
    const float* __restrict__ agg, const float* __restrict__ hin,
    const float* __restrict__ inv, const float* __restrict__ Wl,
    const float* __restrict__ Wr, const float* __restrict__ bias,
    float* __restrict__ hout, int n) {
    __shared__ float wl_s[32][128];
    __shared__ float wr_s[32][128];
    __shared__ float a_s[32][36];   // padded rows, 16B-aligned float4 stores
    __shared__ float h_s[32][36];
    __shared__ float inv_s[32];

    const int t  = threadIdx.x;
    const int o  = t & 127;
    const int nh = t >> 7;          // 0 or 1: which 16-node half this thread owns
    const int n0 = blockIdx.x * 32;

    if (t < 32) {
        int node = n0 + t;
        inv_s[t] = (node < n) ? inv[node] : 0.0f;
    }
    __syncthreads();

    float acc[16];
    #pragma unroll
    for (int i = 0; i < 16; ++i) acc[i] = 0.0f;

    for (int f0 = 0; f0 < 128; f0 += 32) {
        // stage W chunk: 128 o x 32 k, transposed into [k][o]
        #pragma unroll
        for (int j = 0; j < 16; ++j) {
            int idx = t + 256 * j;      // 0..4095
            int oo  = idx >> 5;
            int kk  = idx & 31;
            wl_s[kk][oo] = Wl[oo * 128 + f0 + kk];
            wr_s[kk][oo] = Wr[oo * 128 + f0 + kk];
        }
        // stage features: 32 nodes x 32 k, one float4 per thread
        {
            int nd = t >> 3;
            int kq = (t & 7) * 4;
            int node = n0 + nd;
            float4 av = make_float4(0.f, 0.f, 0.f, 0.f);
            float4 hv = make_float4(0.f, 0.f, 0.f, 0.f);
            if (node < n) {
                av = *(const float4*)(&agg[(size_t)node * 128 + f0 + kq]);
                hv = *(const float4*)(&hin[(size_t)node * 128 + f0 + kq]);
            }
            float iv = inv_s[nd];
            a_s[nd][kq + 0] = av.x * iv;
            a_s[nd][kq + 1] = av.y * iv;
            a_s[nd][kq + 2] = av.z * iv;
            a_s[nd][kq + 3] = av.w * iv;
            h_s[nd][kq + 0] = hv.x;
            h_s[nd][kq + 1] = hv.y;
            h_s[nd][kq + 2] = hv.z;
            h_s[nd][kq + 3] = hv.w;
        }
        __syncthreads();
        #pragma unroll
        for (int k = 0; k < 32; ++k) {
            float wl = wl_s[k][o];
            float wr = wr_s[k][o];
            #pragma unroll
            for (int i = 0; i < 16; ++i) {
                int nd = nh * 16 + i;
                acc[i] = fmaf(a_s[nd][k], wl, acc[i]);
                acc[i] = fmaf(h_s[nd][k], wr, acc[i]);
            }
        }
        __syncthreads();
    }

    float bo = bias[o];
    #pragma unroll
    for (int i = 0; i < 16; ++i) {
        int node = n0 + nh * 16 + i;
        if (node < n) {
            hout[(size_t)node * 128 + o] = fmaxf(acc[i] + bo, 0.0f);
        }
    }
}

// head: 128 -> 4 (no relu).  Thread per (node, o).
__global__ void head_kernel(const float* __restrict__ h,
                            const float* __restrict__ Wh,
                            const float* __restrict__ bh,
                            float* __restrict__ out, int n) {
    int idx = blockIdx.x * 256 + threadIdx.x;
    if (idx >= n * 4) return;
    int node = idx >> 2;
    int o = idx & 3;
    const float* hr = h + (size_t)node * 128;
    const float* wr = Wh + o * 128;
    float acc = bh[o];
    #pragma unroll 4
    for (int f = 0; f < 128; f += 4) {
        acc = fmaf(hr[f + 0], wr[f + 0], acc);
        acc = fmaf(hr[f + 1], wr[f + 1], acc);
        acc = fmaf(hr[f + 2], wr[f + 2], acc);
        acc = fmaf(hr[f + 3], wr[f + 3], acc);
    }
    out[idx] = acc;
}

extern "C" void kernel_launch(void* const* d_in, const int* in_sizes, int n_in,
                              void* d_out, int out_size, void* d_ws, size_t ws_size,
                              hipStream_t stream) {
    const float* x   = (const float*)d_in[0];
    const int*   ei  = (const int*)d_in[1];
    const float* Wl1 = (const float*)d_in[2];
    const float* Wr1 = (const float*)d_in[3];
    const float* b1  = (const float*)d_in[4];
    const float* Wl2 = (const float*)d_in[5];
    const float* Wr2 = (const float*)d_in[6];
    const float* b2  = (const float*)d_in[7];
    const float* Wl3 = (const float*)d_in[8];
    const float* Wr3 = (const float*)d_in[9];
    const float* b3  = (const float*)d_in[10];
    const float* Wh  = (const float*)d_in[11];
    const float* bh  = (const float*)d_in[12];
    float* out = (float*)d_out;

    const int N = in_sizes[0] / 16;
    const int E = in_sizes[1] / 2;
    const int* src = ei;
    const int* dst = ei + E;

    float* cnt = (float*)d_ws;                 // N   (becomes inv after inv_kernel)
    float* agg = cnt + N;                      // N*128 (layer1 uses first N*16)
    float* hA  = agg + (size_t)N * 128;        // N*128
    float* hB  = hA  + (size_t)N * 128;        // N*128

    const int B = 256;
    auto blocks = [](long total, int b) { return (int)((total + b - 1) / b); };

    // degree counts -> inverse
    zero_kernel<<<blocks(N / 4, B), B, 0, stream>>>((float4*)cnt, N / 4);
    count_kernel<<<blocks(E, B), B, 0, stream>>>(dst, cnt, E);
    inv_kernel<<<blocks(N, B), B, 0, stream>>>(cnt, N);
    const float* inv = cnt;

    // ---- layer 1: 16 -> 128 ----
    zero_kernel<<<blocks((long)N * 16 / 4, B), B, 0, stream>>>((float4*)agg, N * 16 / 4);
    scatter16_kernel<<<blocks((long)E * 16, B), B, 0, stream>>>(x, src, dst, agg, E * 16);
    layer16_kernel<<<blocks(N, 2), B, 0, stream>>>(agg, x, inv, Wl1, Wr1, b1, hA, N);

    // ---- layer 2: 128 -> 128 ----
    zero_kernel<<<blocks((long)N * 128 / 4, B), B, 0, stream>>>((float4*)agg, N * 32);
    scatter128_kernel<<<blocks((long)E * 128, B), B, 0, stream>>>(hA, src, dst, agg, E * 128);
    layer128_kernel<<<blocks(N, 32), B, 0, stream>>>(agg, hA, inv, Wl2, Wr2, b2, hB, N);

    // ---- layer 3: 128 -> 128 ----
    zero_kernel<<<blocks((long)N * 128 / 4, B), B, 0, stream>>>((float4*)agg, N * 32);
    scatter128_kernel<<<blocks((long)E * 128, B), B, 0, stream>>>(hB, src, dst, agg, E * 128);
    layer128_kernel<<<blocks(N, 32), B, 0, stream>>>(agg, hB, inv, Wl3, Wr3, b3, hA, N);

    // ---- head: 128 -> 4 ----
    head_kernel<<<blocks((long)N * 4, B), B, 0, stream>>>(hA, Wh, bh, out, N);
}

// Round 2
// 650.204 us; speedup vs baseline: 2.2128x; 2.2128x over previous
//
#include <hip/hip_runtime.h>
#include <hip/hip_bf16.h>

// ---------------------------------------------------------------------------
// GraphSAGE (3x SAGEConv mean + linear head), fp32, CSR gather formulation.
// Per launch:
//   zero(deg); count(dst); scan -> rowptr/cursor/inv
//   fill_csr -> col
//   aggregate16(x)   -> agg16 ; layer16  -> hA   (16 -> 128, relu)
//   aggregate128(hA) -> agg   ; layer128 -> hB   (128 -> 128, relu)
//   aggregate128(hB) -> agg   ; layer128 -> hA   (128 -> 128, relu)
//   head(hA) -> out                               (128 -> 4)
// No atomic feature scatters; aggregation is a conflict-free gather with
// coalesced 512B row reads. layer128 is register-tiled (8n x 4o per thread,
// all LDS traffic ds_read_b128) to be VALU-bound, not LDS-issue-bound.
// ---------------------------------------------------------------------------

__global__ void zero_int_kernel(int* __restrict__ p, int n) {
    int i = blockIdx.x * 256 + threadIdx.x;
    if (i < n) p[i] = 0;
}

__global__ void count_deg_kernel(const int* __restrict__ dst, int* __restrict__ deg, int E) {
    int e = blockIdx.x * 256 + threadIdx.x;
    if (e < E) atomicAdd(&deg[dst[e]], 1);
}

// single-block exclusive scan over deg -> rowptr, cursor copy, inv = 1/max(deg,1)
__global__ __launch_bounds__(1024) void scan_kernel(
    const int* __restrict__ deg, int* __restrict__ rowptr, int* __restrict__ cursor,
    float* __restrict__ inv, int N) {
    __shared__ int s[1024];
    const int t = threadIdx.x;
    const int C = (N + 1023) >> 10;
    const int lo = t * C;
    const int hi = min(lo + C, N);
    int sum = 0;
    for (int i = lo; i < hi; ++i) sum += deg[i];
    s[t] = sum;
    __syncthreads();
    for (int off = 1; off < 1024; off <<= 1) {
        int v = (t >= off) ? s[t - off] : 0;
        __syncthreads();
        s[t] += v;
        __syncthreads();
    }
    int base = (t == 0) ? 0 : s[t - 1];
    for (int i = lo; i < hi; ++i) {
        rowptr[i] = base;
        cursor[i] = base;
        int d = deg[i];
        inv[i] = 1.0f / (float)max(d, 1);
        base += d;
    }
    if (t == 0) rowptr[N] = s[1023];
}

__global__ void fill_csr_kernel(const int* __restrict__ src, const int* __restrict__ dst,
                                int* __restrict__ cursor, int* __restrict__ col, int E) {
    int e = blockIdx.x * 256 + threadIdx.x;
    if (e >= E) return;
    int pos = atomicAdd(&cursor[dst[e]], 1);
    col[pos] = src[e];
}

// 16-feat mean aggregate: 16 nodes/block, 16 lanes per node (1 feat/lane)
__global__ __launch_bounds__(256) void aggregate16_kernel(
    const float* __restrict__ x, const int* __restrict__ rowptr,
    const int* __restrict__ col, const float* __restrict__ inv,
    float* __restrict__ agg, int N) {
    const int t = threadIdx.x;
    const int node = blockIdx.x * 16 + (t >> 4);
    const int f = t & 15;
    if (node >= N) return;
    const int lo = rowptr[node], hi = rowptr[node + 1];
    float acc = 0.0f;
    for (int e = lo; e < hi; ++e)
        acc += x[col[e] * 16 + f];
    agg[node * 16 + f] = acc * inv[node];
}

// 128-feat mean aggregate: wave per node, float2 per lane (coalesced 512B rows)
__global__ __launch_bounds__(256) void aggregate128_kernel(
    const float* __restrict__ h, const int* __restrict__ rowptr,
    const int* __restrict__ col, const float* __restrict__ inv,
    float* __restrict__ agg, int N) {
    const int t = threadIdx.x;
    const int node = blockIdx.x * 4 + (t >> 6);
    const int lane = t & 63;
    if (node >= N) return;
    const int lo = rowptr[node], hi = rowptr[node + 1];
    float ax = 0.0f, ay = 0.0f;
    int e = lo;
    for (; e + 1 < hi; e += 2) {           // 2-way unroll: overlap row-load latency
        int s0 = col[e], s1 = col[e + 1];
        float2 v0 = *(const float2*)&h[(size_t)s0 * 128 + lane * 2];
        float2 v1 = *(const float2*)&h[(size_t)s1 * 128 + lane * 2];
        ax += v0.x + v1.x;
        ay += v0.y + v1.y;
    }
    if (e < hi) {
        float2 v0 = *(const float2*)&h[(size_t)col[e] * 128 + lane * 2];
        ax += v0.x;
        ay += v0.y;
    }
    float iv = inv[node];
    *(float2*)&agg[(size_t)node * 128 + lane * 2] = make_float2(ax * iv, ay * iv);
}

// layer 1: 16 -> 128, agg16 already holds the mean
__global__ __launch_bounds__(256) void layer16_kernel(
    const float* __restrict__ agg16, const float* __restrict__ x,
    const float* __restrict__ Wl, const float* __restrict__ Wr,
    const float* __restrict__ bias, float* __restrict__ hout, int n) {
    const int t = threadIdx.x;
    const int o = t & 127;
    const int node = blockIdx.x * 2 + (t >> 7);
    if (node >= n) return;
    const float* wlr = Wl + o * 16;
    const float* wrr = Wr + o * 16;
    const float* ar = agg16 + node * 16;
    const float* xr = x + node * 16;
    float acc = bias[o];
    #pragma unroll
    for (int f = 0; f < 16; ++f) {
        acc = fmaf(ar[f], wlr[f], acc);
        acc = fmaf(xr[f], wrr[f], acc);
    }
    hout[node * 128 + o] = fmaxf(acc, 0.0f);
}

// layer 2/3: 128 -> 128. Block tile 64 nodes x 128 outs; thread tile 8n x 4o.
// All LDS compute reads are ds_read_b128; pad 36 keeps float4 alignment and
// spreads banks (uniform 8 accesses per 4-bank group = bandwidth minimum).
__global__ __launch_bounds__(256) void layer128_kernel(
    const float* __restrict__ agg, const float* __restrict__ hin,
    const float* __restrict__ Wl, const float* __restrict__ Wr,
    const float* __restrict__ bias, float* __restrict__ hout, int n) {
    __shared__ float wl_s[128][36];
    __shared__ float wr_s[128][36];
    __shared__ float a_s[64][36];
    __shared__ float h_s[64][36];

    const int t = threadIdx.x;
    const int n0 = blockIdx.x * 64;
    const int o0 = (t & 31) * 4;       // 4 consecutive outputs
    const int nd0 = (t >> 5) * 8;      // 8 consecutive nodes

    float acc[8][4];
    #pragma unroll
    for (int i = 0; i < 8; ++i)
        #pragma unroll
        for (int j = 0; j < 4; ++j) acc[i][j] = 0.0f;

    for (int f0 = 0; f0 < 128; f0 += 32) {
        // stage W chunk: 128 o x 32 k (coalesced global, conflict-free LDS)
        #pragma unroll
        for (int j = 0; j < 4; ++j) {
            int q = t + 256 * j;
            int oo = q >> 3, kk = (q & 7) * 4;
            *(float4*)&wl_s[oo][kk] = *(const float4*)&Wl[oo * 128 + f0 + kk];
            *(float4*)&wr_s[oo][kk] = *(const float4*)&Wr[oo * 128 + f0 + kk];
        }
        // stage features: 64 nodes x 32 k
        #pragma unroll
        for (int j = 0; j < 2; ++j) {
            int q = t + 256 * j;
            int nd = q >> 3, kk = (q & 7) * 4;
            int node = n0 + nd;
            float4 av = make_float4(0.f, 0.f, 0.f, 0.f);
            float4 hv = make_float4(0.f, 0.f, 0.f, 0.f);
            if (node < n) {
                av = *(const float4*)&agg[(size_t)node * 128 + f0 + kk];
                hv = *(const float4*)&hin[(size_t)node * 128 + f0 + kk];
            }
            *(float4*)&a_s[nd][kk] = av;
            *(float4*)&h_s[nd][kk] = hv;
        }
        __syncthreads();

        #pragma unroll
        for (int k4 = 0; k4 < 32; k4 += 4) {
            // agg * Wl
            {
                float4 w0 = *(float4*)&wl_s[o0 + 0][k4];
                float4 w1 = *(float4*)&wl_s[o0 + 1][k4];
                float4 w2 = *(float4*)&wl_s[o0 + 2][k4];
                float4 w3 = *(float4*)&wl_s[o0 + 3][k4];
                #pragma unroll
                for (int i = 0; i < 8; ++i) {
                    float4 v = *(float4*)&a_s[nd0 + i][k4];
                    acc[i][0] = fmaf(v.x, w0.x, fmaf(v.y, w0.y, fmaf(v.z, w0.z, fmaf(v.w, w0.w, acc[i][0]))));
                    acc[i][1] = fmaf(v.x, w1.x, fmaf(v.y, w1.y, fmaf(v.z, w1.z, fmaf(v.w, w1.w, acc[i][1]))));
                    acc[i][2] = fmaf(v.x, w2.x, fmaf(v.y, w2.y, fmaf(v.z, w2.z, fmaf(v.w, w2.w, acc[i][2]))));
                    acc[i][3] = fmaf(v.x, w3.x, fmaf(v.y, w3.y, fmaf(v.z, w3.z, fmaf(v.w, w3.w, acc[i][3]))));
                }
            }
            // h * Wr
            {
                float4 w0 = *(float4*)&wr_s[o0 + 0][k4];
                float4 w1 = *(float4*)&wr_s[o0 + 1][k4];
                float4 w2 = *(float4*)&wr_s[o0 + 2][k4];
                float4 w3 = *(float4*)&wr_s[o0 + 3][k4];
                #pragma unroll
                for (int i = 0; i < 8; ++i) {
                    float4 v = *(float4*)&h_s[nd0 + i][k4];
                    acc[i][0] = fmaf(v.x, w0.x, fmaf(v.y, w0.y, fmaf(v.z, w0.z, fmaf(v.w, w0.w, acc[i][0]))));
                    acc[i][1] = fmaf(v.x, w1.x, fmaf(v.y, w1.y, fmaf(v.z, w1.z, fmaf(v.w, w1.w, acc[i][1]))));
                    acc[i][2] = fmaf(v.x, w2.x, fmaf(v.y, w2.y, fmaf(v.z, w2.z, fmaf(v.w, w2.w, acc[i][2]))));
                    acc[i][3] = fmaf(v.x, w3.x, fmaf(v.y, w3.y, fmaf(v.z, w3.z, fmaf(v.w, w3.w, acc[i][3]))));
                }
            }
        }
        __syncthreads();
    }

    float4 b = *(const float4*)&bias[o0];
    #pragma unroll
    for (int i = 0; i < 8; ++i) {
        int node = n0 + nd0 + i;
        if (node < n) {
            float4 r;
            r.x = fmaxf(acc[i][0] + b.x, 0.0f);
            r.y = fmaxf(acc[i][1] + b.y, 0.0f);
            r.z = fmaxf(acc[i][2] + b.z, 0.0f);
            r.w = fmaxf(acc[i][3] + b.w, 0.0f);
            *(float4*)&hout[(size_t)node * 128 + o0] = r;
        }
    }
}

// head: 128 -> 4 (no relu)
__global__ void head_kernel(const float* __restrict__ h,
                            const float* __restrict__ Wh,
                            const float* __restrict__ bh,
                            float* __restrict__ out, int n) {
    int idx = blockIdx.x * 256 + threadIdx.x;
    if (idx >= n * 4) return;
    int node = idx >> 2;
    int o = idx & 3;
    const float* hr = h + (size_t)node * 128;
    const float* wr = Wh + o * 128;
    float acc = bh[o];
    #pragma unroll 4
    for (int f = 0; f < 128; f += 4) {
        acc = fmaf(hr[f + 0], wr[f + 0], acc);
        acc = fmaf(hr[f + 1], wr[f + 1], acc);
        acc = fmaf(hr[f + 2], wr[f + 2], acc);
        acc = fmaf(hr[f + 3], wr[f + 3], acc);
    }
    out[idx] = acc;
}

extern "C" void kernel_launch(void* const* d_in, const int* in_sizes, int n_in,
                              void* d_out, int out_size, void* d_ws, size_t ws_size,
                              hipStream_t stream) {
    const float* x   = (const float*)d_in[0];
    const int*   ei  = (const int*)d_in[1];
    const float* Wl1 = (const float*)d_in[2];
    const float* Wr1 = (const float*)d_in[3];
    const float* b1  = (const float*)d_in[4];
    const float* Wl2 = (const float*)d_in[5];
    const float* Wr2 = (const float*)d_in[6];
    const float* b2  = (const float*)d_in[7];
    const float* Wl3 = (const float*)d_in[8];
    const float* Wr3 = (const float*)d_in[9];
    const float* b3  = (const float*)d_in[10];
    const float* Wh  = (const float*)d_in[11];
    const float* bh  = (const float*)d_in[12];
    float* out = (float*)d_out;

    const int N = in_sizes[0] / 16;
    const int E = in_sizes[1] / 2;
    const int* src = ei;
    const int* dst = ei + E;

    // workspace layout (element offsets keep every array 16B-aligned)
    int* deg     = (int*)d_ws;                    // N
    int* rowptr  = deg + N;                       // N+1 (padded to N+8)
    int* cursor  = rowptr + (N + 8);              // N
    int* col     = cursor + N;                    // E
    float* inv   = (float*)(col + E);             // N
    float* agg   = inv + N;                       // N*128 (layer1 uses N*16)
    float* hA    = agg + (size_t)N * 128;         // N*128
    float* hB    = hA + (size_t)N * 128;          // N*128

    const int B = 256;
    auto blocks = [](long total, int b) { return (int)((total + b - 1) / b); };

    // ---- CSR build ----
    zero_int_kernel<<<blocks(N, B), B, 0, stream>>>(deg, N);
    count_deg_kernel<<<blocks(E, B), B, 0, stream>>>(dst, deg, E);
    scan_kernel<<<1, 1024, 0, stream>>>(deg, rowptr, cursor, inv, N);
    fill_csr_kernel<<<blocks(E, B), B, 0, stream>>>(src, dst, cursor, col, E);

    // ---- layer 1: 16 -> 128 ----
    aggregate16_kernel<<<blocks(N, 16), B, 0, stream>>>(x, rowptr, col, inv, agg, N);
    layer16_kernel<<<blocks(N, 2), B, 0, stream>>>(agg, x, Wl1, Wr1, b1, hA, N);

    // ---- layer 2: 128 -> 128 ----
    aggregate128_kernel<<<blocks(N, 4), B, 0, stream>>>(hA, rowptr, col, inv, agg, N);
    layer128_kernel<<<blocks(N, 64), B, 0, stream>>>(agg, hA, Wl2, Wr2, b2, hB, N);

    // ---- layer 3: 128 -> 128 ----
    aggregate128_kernel<<<blocks(N, 4), B, 0, stream>>>(hB, rowptr, col, inv, agg, N);
    layer128_kernel<<<blocks(N, 64), B, 0, stream>>>(agg, hB, Wl3, Wr3, b3, hA, N);

    // ---- head: 128 -> 4 ----
    head_kernel<<<blocks((long)N * 4, B), B, 0, stream>>>(hA, Wh, bh, out, N);
}

// Round 3
// 530.881 us; speedup vs baseline: 2.7102x; 1.2248x over previous
//
#include <hip/hip_runtime.h>
#include <hip/hip_bf16.h>

// ---------------------------------------------------------------------------
// GraphSAGE (3x SAGEConv mean + linear head), fp32, CSR gather formulation.
// Per launch:
//   zero(deg); count(dst); hierarchical scan -> rowptr/cursor/inv
//   fill_csr -> col
//   aggregate16(x)   -> agg16 ; layer16  -> hA   (16 -> 128, relu)
//   aggregate128(hA) -> agg   ; layer128 -> hB   (128 -> 128, relu)
//   aggregate128(hB) -> agg   ; layer128 -> hA   (128 -> 128, relu)
//   head(hA) -> out                               (128 -> 4)
// Round-3 change: single-block scan (133us, 1 CU busy) replaced by a
// 2-kernel hierarchical scan (25 blocks + 25 blocks), ~10us total.
// ---------------------------------------------------------------------------

#define SCAN_CHUNK 2048   // elements per block in the scan (256 thr x 8)

__global__ void zero_int_kernel(int* __restrict__ p, int n) {
    int i = blockIdx.x * 256 + threadIdx.x;
    if (i < n) p[i] = 0;
}

__global__ void count_deg_kernel(const int* __restrict__ dst, int* __restrict__ deg, int E) {
    int e = blockIdx.x * 256 + threadIdx.x;
    if (e < E) atomicAdd(&deg[dst[e]], 1);
}

// stage 1: per-block sums of deg (8 elements per thread, tree reduce)
__global__ __launch_bounds__(256) void scan_partial_kernel(
    const int* __restrict__ deg, int* __restrict__ blocksum, int N) {
    __shared__ int s[256];
    const int t = threadIdx.x;
    const int base = blockIdx.x * SCAN_CHUNK + t * 8;
    int sum = 0;
    #pragma unroll
    for (int j = 0; j < 8; ++j) {
        int i = base + j;
        if (i < N) sum += deg[i];
    }
    s[t] = sum;
    __syncthreads();
    #pragma unroll
    for (int off = 128; off > 0; off >>= 1) {
        if (t < off) s[t] += s[t + off];
        __syncthreads();
    }
    if (t == 0) blocksum[blockIdx.x] = s[0];
}

// stage 2: each block scans its chunk; block offset = serial sum of the
// (<=32) preceding block sums. Writes rowptr (exclusive), cursor, inv.
__global__ __launch_bounds__(256) void scan_final_kernel(
    const int* __restrict__ deg, const int* __restrict__ blocksum,
    int* __restrict__ rowptr, int* __restrict__ cursor,
    float* __restrict__ inv, int N) {
    __shared__ int s[256];
    __shared__ int blockoff_s;
    const int t = threadIdx.x;
    if (t == 0) {
        int off = 0;
        for (int b = 0; b < (int)blockIdx.x; ++b) off += blocksum[b];
        blockoff_s = off;
    }
    const int base = blockIdx.x * SCAN_CHUNK + t * 8;
    int v[8];
    int sum = 0;
    #pragma unroll
    for (int j = 0; j < 8; ++j) {
        int i = base + j;
        v[j] = (i < N) ? deg[i] : 0;
        sum += v[j];
    }
    s[t] = sum;
    __syncthreads();
    // inclusive Hillis-Steele over per-thread sums
    for (int off = 1; off < 256; off <<= 1) {
        int val = (t >= off) ? s[t - off] : 0;
        __syncthreads();
        s[t] += val;
        __syncthreads();
    }
    int run = blockoff_s + ((t == 0) ? 0 : s[t - 1]);
    #pragma unroll
    for (int j = 0; j < 8; ++j) {
        int i = base + j;
        if (i < N) {
            rowptr[i] = run;
            cursor[i] = run;
            inv[i] = 1.0f / (float)max(v[j], 1);
            run += v[j];
        }
    }
    // thread 255 of the last block holds the grand total
    if ((int)blockIdx.x == (int)gridDim.x - 1 && t == 255) rowptr[N] = run;
}

__global__ void fill_csr_kernel(const int* __restrict__ src, const int* __restrict__ dst,
                                int* __restrict__ cursor, int* __restrict__ col, int E) {
    int e = blockIdx.x * 256 + threadIdx.x;
    if (e >= E) return;
    int pos = atomicAdd(&cursor[dst[e]], 1);
    col[pos] = src[e];
}

// 16-feat mean aggregate: 16 nodes/block, 16 lanes per node (1 feat/lane)
__global__ __launch_bounds__(256) void aggregate16_kernel(
    const float* __restrict__ x, const int* __restrict__ rowptr,
    const int* __restrict__ col, const float* __restrict__ inv,
    float* __restrict__ agg, int N) {
    const int t = threadIdx.x;
    const int node = blockIdx.x * 16 + (t >> 4);
    const int f = t & 15;
    if (node >= N) return;
    const int lo = rowptr[node], hi = rowptr[node + 1];
    float acc = 0.0f;
    for (int e = lo; e < hi; ++e)
        acc += x[col[e] * 16 + f];
    agg[node * 16 + f] = acc * inv[node];
}

// 128-feat mean aggregate: wave per node, float2 per lane (coalesced 512B rows)
__global__ __launch_bounds__(256) void aggregate128_kernel(
    const float* __restrict__ h, const int* __restrict__ rowptr,
    const int* __restrict__ col, const float* __restrict__ inv,
    float* __restrict__ agg, int N) {
    const int t = threadIdx.x;
    const int node = blockIdx.x * 4 + (t >> 6);
    const int lane = t & 63;
    if (node >= N) return;
    const int lo = rowptr[node], hi = rowptr[node + 1];
    float ax = 0.0f, ay = 0.0f;
    int e = lo;
    for (; e + 1 < hi; e += 2) {           // 2-way unroll: overlap row-load latency
        int s0 = col[e], s1 = col[e + 1];
        float2 v0 = *(const float2*)&h[(size_t)s0 * 128 + lane * 2];
        float2 v1 = *(const float2*)&h[(size_t)s1 * 128 + lane * 2];
        ax += v0.x + v1.x;
        ay += v0.y + v1.y;
    }
    if (e < hi) {
        float2 v0 = *(const float2*)&h[(size_t)col[e] * 128 + lane * 2];
        ax += v0.x;
        ay += v0.y;
    }
    float iv = inv[node];
    *(float2*)&agg[(size_t)node * 128 + lane * 2] = make_float2(ax * iv, ay * iv);
}

// layer 1: 16 -> 128, agg16 already holds the mean
__global__ __launch_bounds__(256) void layer16_kernel(
    const float* __restrict__ agg16, const float* __restrict__ x,
    const float* __restrict__ Wl, const float* __restrict__ Wr,
    const float* __restrict__ bias, float* __restrict__ hout, int n) {
    const int t = threadIdx.x;
    const int o = t & 127;
    const int node = blockIdx.x * 2 + (t >> 7);
    if (node >= n) return;
    const float* wlr = Wl + o * 16;
    const float* wrr = Wr + o * 16;
    const float* ar = agg16 + node * 16;
    const float* xr = x + node * 16;
    float acc = bias[o];
    #pragma unroll
    for (int f = 0; f < 16; ++f) {
        acc = fmaf(ar[f], wlr[f], acc);
        acc = fmaf(xr[f], wrr[f], acc);
    }
    hout[node * 128 + o] = fmaxf(acc, 0.0f);
}

// layer 2/3: 128 -> 128. Block tile 64 nodes x 128 outs; thread tile 8n x 4o.
// All LDS compute reads are ds_read_b128; pad 36 keeps float4 alignment.
__global__ __launch_bounds__(256) void layer128_kernel(
    const float* __restrict__ agg, const float* __restrict__ hin,
    const float* __restrict__ Wl, const float* __restrict__ Wr,
    const float* __restrict__ bias, float* __restrict__ hout, int n) {
    __shared__ float wl_s[128][36];
    __shared__ float wr_s[128][36];
    __shared__ float a_s[64][36];
    __shared__ float h_s[64][36];

    const int t = threadIdx.x;
    const int n0 = blockIdx.x * 64;
    const int o0 = (t & 31) * 4;       // 4 consecutive outputs
    const int nd0 = (t >> 5) * 8;      // 8 consecutive nodes

    float acc[8][4];
    #pragma unroll
    for (int i = 0; i < 8; ++i)
        #pragma unroll
        for (int j = 0; j < 4; ++j) acc[i][j] = 0.0f;

    for (int f0 = 0; f0 < 128; f0 += 32) {
        // stage W chunk: 128 o x 32 k (coalesced global, conflict-free LDS)
        #pragma unroll
        for (int j = 0; j < 4; ++j) {
            int q = t + 256 * j;
            int oo = q >> 3, kk = (q & 7) * 4;
            *(float4*)&wl_s[oo][kk] = *(const float4*)&Wl[oo * 128 + f0 + kk];
            *(float4*)&wr_s[oo][kk] = *(const float4*)&Wr[oo * 128 + f0 + kk];
        }
        // stage features: 64 nodes x 32 k
        #pragma unroll
        for (int j = 0; j < 2; ++j) {
            int q = t + 256 * j;
            int nd = q >> 3, kk = (q & 7) * 4;
            int node = n0 + nd;
            float4 av = make_float4(0.f, 0.f, 0.f, 0.f);
            float4 hv = make_float4(0.f, 0.f, 0.f, 0.f);
            if (node < n) {
                av = *(const float4*)&agg[(size_t)node * 128 + f0 + kk];
                hv = *(const float4*)&hin[(size_t)node * 128 + f0 + kk];
            }
            *(float4*)&a_s[nd][kk] = av;
            *(float4*)&h_s[nd][kk] = hv;
        }
        __syncthreads();

        #pragma unroll
        for (int k4 = 0; k4 < 32; k4 += 4) {
            {
                float4 w0 = *(float4*)&wl_s[o0 + 0][k4];
                float4 w1 = *(float4*)&wl_s[o0 + 1][k4];
                float4 w2 = *(float4*)&wl_s[o0 + 2][k4];
                float4 w3 = *(float4*)&wl_s[o0 + 3][k4];
                #pragma unroll
                for (int i = 0; i < 8; ++i) {
                    float4 v = *(float4*)&a_s[nd0 + i][k4];
                    acc[i][0] = fmaf(v.x, w0.x, fmaf(v.y, w0.y, fmaf(v.z, w0.z, fmaf(v.w, w0.w, acc[i][0]))));
                    acc[i][1] = fmaf(v.x, w1.x, fmaf(v.y, w1.y, fmaf(v.z, w1.z, fmaf(v.w, w1.w, acc[i][1]))));
                    acc[i][2] = fmaf(v.x, w2.x, fmaf(v.y, w2.y, fmaf(v.z, w2.z, fmaf(v.w, w2.w, acc[i][2]))));
                    acc[i][3] = fmaf(v.x, w3.x, fmaf(v.y, w3.y, fmaf(v.z, w3.z, fmaf(v.w, w3.w, acc[i][3]))));
                }
            }
            {
                float4 w0 = *(float4*)&wr_s[o0 + 0][k4];
                float4 w1 = *(float4*)&wr_s[o0 + 1][k4];
                float4 w2 = *(float4*)&wr_s[o0 + 2][k4];
                float4 w3 = *(float4*)&wr_s[o0 + 3][k4];
                #pragma unroll
                for (int i = 0; i < 8; ++i) {
                    float4 v = *(float4*)&h_s[nd0 + i][k4];
                    acc[i][0] = fmaf(v.x, w0.x, fmaf(v.y, w0.y, fmaf(v.z, w0.z, fmaf(v.w, w0.w, acc[i][0]))));
                    acc[i][1] = fmaf(v.x, w1.x, fmaf(v.y, w1.y, fmaf(v.z, w1.z, fmaf(v.w, w1.w, acc[i][1]))));
                    acc[i][2] = fmaf(v.x, w2.x, fmaf(v.y, w2.y, fmaf(v.z, w2.z, fmaf(v.w, w2.w, acc[i][2]))));
                    acc[i][3] = fmaf(v.x, w3.x, fmaf(v.y, w3.y, fmaf(v.z, w3.z, fmaf(v.w, w3.w, acc[i][3]))));
                }
            }
        }
        __syncthreads();
    }

    float4 b = *(const float4*)&bias[o0];
    #pragma unroll
    for (int i = 0; i < 8; ++i) {
        int node = n0 + nd0 + i;
        if (node < n) {
            float4 r;
            r.x = fmaxf(acc[i][0] + b.x, 0.0f);
            r.y = fmaxf(acc[i][1] + b.y, 0.0f);
            r.z = fmaxf(acc[i][2] + b.z, 0.0f);
            r.w = fmaxf(acc[i][3] + b.w, 0.0f);
            *(float4*)&hout[(size_t)node * 128 + o0] = r;
        }
    }
}

// head: 128 -> 4 (no relu)
__global__ void head_kernel(const float* __restrict__ h,
                            const float* __restrict__ Wh,
                            const float* __restrict__ bh,
                            float* __restrict__ out, int n) {
    int idx = blockIdx.x * 256 + threadIdx.x;
    if (idx >= n * 4) return;
    int node = idx >> 2;
    int o = idx & 3;
    const float* hr = h + (size_t)node * 128;
    const float* wr = Wh + o * 128;
    float acc = bh[o];
    #pragma unroll 4
    for (int f = 0; f < 128; f += 4) {
        acc = fmaf(hr[f + 0], wr[f + 0], acc);
        acc = fmaf(hr[f + 1], wr[f + 1], acc);
        acc = fmaf(hr[f + 2], wr[f + 2], acc);
        acc = fmaf(hr[f + 3], wr[f + 3], acc);
    }
    out[idx] = acc;
}

extern "C" void kernel_launch(void* const* d_in, const int* in_sizes, int n_in,
                              void* d_out, int out_size, void* d_ws, size_t ws_size,
                              hipStream_t stream) {
    const float* x   = (const float*)d_in[0];
    const int*   ei  = (const int*)d_in[1];
    const float* Wl1 = (const float*)d_in[2];
    const float* Wr1 = (const float*)d_in[3];
    const float* b1  = (const float*)d_in[4];
    const float* Wl2 = (const float*)d_in[5];
    const float* Wr2 = (const float*)d_in[6];
    const float* b2  = (const float*)d_in[7];
    const float* Wl3 = (const float*)d_in[8];
    const float* Wr3 = (const float*)d_in[9];
    const float* b3  = (const float*)d_in[10];
    const float* Wh  = (const float*)d_in[11];
    const float* bh  = (const float*)d_in[12];
    float* out = (float*)d_out;

    const int N = in_sizes[0] / 16;
    const int E = in_sizes[1] / 2;
    const int* src = ei;
    const int* dst = ei + E;

    const int nScanBlocks = (N + SCAN_CHUNK - 1) / SCAN_CHUNK;

    // workspace layout (element offsets keep every array 16B-aligned)
    int* deg      = (int*)d_ws;                   // N
    int* rowptr   = deg + N;                      // N+1 (padded to N+8)
    int* cursor   = rowptr + (N + 8);             // N
    int* blocksum = cursor + N;                   // nScanBlocks (padded 64)
    int* col      = blocksum + 64;                // E
    float* inv    = (float*)(col + E);            // N
    float* agg    = inv + N;                      // N*128 (layer1 uses N*16)
    float* hA     = agg + (size_t)N * 128;        // N*128
    float* hB     = hA + (size_t)N * 128;         // N*128

    const int B = 256;
    auto blocks = [](long total, int b) { return (int)((total + b - 1) / b); };

    // ---- CSR build ----
    zero_int_kernel<<<blocks(N, B), B, 0, stream>>>(deg, N);
    count_deg_kernel<<<blocks(E, B), B, 0, stream>>>(dst, deg, E);
    scan_partial_kernel<<<nScanBlocks, B, 0, stream>>>(deg, blocksum, N);
    scan_final_kernel<<<nScanBlocks, B, 0, stream>>>(deg, blocksum, rowptr, cursor, inv, N);
    fill_csr_kernel<<<blocks(E, B), B, 0, stream>>>(src, dst, cursor, col, E);

    // ---- layer 1: 16 -> 128 ----
    aggregate16_kernel<<<blocks(N, 16), B, 0, stream>>>(x, rowptr, col, inv, agg, N);
    layer16_kernel<<<blocks(N, 2), B, 0, stream>>>(agg, x, Wl1, Wr1, b1, hA, N);

    // ---- layer 2: 128 -> 128 ----
    aggregate128_kernel<<<blocks(N, 4), B, 0, stream>>>(hA, rowptr, col, inv, agg, N);
    layer128_kernel<<<blocks(N, 64), B, 0, stream>>>(agg, hA, Wl2, Wr2, b2, hB, N);

    // ---- layer 3: 128 -> 128 ----
    aggregate128_kernel<<<blocks(N, 4), B, 0, stream>>>(hB, rowptr, col, inv, agg, N);
    layer128_kernel<<<blocks(N, 64), B, 0, stream>>>(agg, hB, Wl3, Wr3, b3, hA, N);

    // ---- head: 128 -> 4 ----
    head_kernel<<<blocks((long)N * 4, B), B, 0, stream>>>(hA, Wh, bh, out, N);
}

// Round 4
// 480.568 us; speedup vs baseline: 2.9939x; 1.1047x over previous
//
#include <hip/hip_runtime.h>
#include <hip/hip_bf16.h>

// ---------------------------------------------------------------------------
// GraphSAGE (3x SAGEConv mean + linear head), CSR gather formulation.
// Hidden activations stored as bf16 (halves gather/stream bytes); all
// accumulation in fp32. layer128: conflict-free LDS (strided o-mapping),
// 52KB LDS -> 3 blocks/CU.
// ---------------------------------------------------------------------------

#define SCAN_CHUNK 2048

typedef unsigned short bf16_t;
typedef unsigned int uint32;

__device__ __forceinline__ bf16_t f2bf(float f) {
    uint32 u = __float_as_uint(f);
    u += 0x7fff + ((u >> 16) & 1);           // round-to-nearest-even
    return (bf16_t)(u >> 16);
}
__device__ __forceinline__ float bf2f(bf16_t b) {
    return __uint_as_float((uint32)b << 16);
}

__global__ void zero_int_kernel(int* __restrict__ p, int n) {
    int i = blockIdx.x * 256 + threadIdx.x;
    if (i < n) p[i] = 0;
}

__global__ void count_deg_kernel(const int* __restrict__ dst, int* __restrict__ deg, int E) {
    int e = blockIdx.x * 256 + threadIdx.x;
    if (e < E) atomicAdd(&deg[dst[e]], 1);
}

__global__ __launch_bounds__(256) void scan_partial_kernel(
    const int* __restrict__ deg, int* __restrict__ blocksum, int N) {
    __shared__ int s[256];
    const int t = threadIdx.x;
    const int base = blockIdx.x * SCAN_CHUNK + t * 8;
    int sum = 0;
    #pragma unroll
    for (int j = 0; j < 8; ++j) {
        int i = base + j;
        if (i < N) sum += deg[i];
    }
    s[t] = sum;
    __syncthreads();
    #pragma unroll
    for (int off = 128; off > 0; off >>= 1) {
        if (t < off) s[t] += s[t + off];
        __syncthreads();
    }
    if (t == 0) blocksum[blockIdx.x] = s[0];
}

__global__ __launch_bounds__(256) void scan_final_kernel(
    const int* __restrict__ deg, const int* __restrict__ blocksum,
    int* __restrict__ rowptr, int* __restrict__ cursor,
    float* __restrict__ inv, int N) {
    __shared__ int s[256];
    __shared__ int blockoff_s;
    const int t = threadIdx.x;
    if (t == 0) {
        int off = 0;
        for (int b = 0; b < (int)blockIdx.x; ++b) off += blocksum[b];
        blockoff_s = off;
    }
    const int base = blockIdx.x * SCAN_CHUNK + t * 8;
    int v[8];
    int sum = 0;
    #pragma unroll
    for (int j = 0; j < 8; ++j) {
        int i = base + j;
        v[j] = (i < N) ? deg[i] : 0;
        sum += v[j];
    }
    s[t] = sum;
    __syncthreads();
    for (int off = 1; off < 256; off <<= 1) {
        int val = (t >= off) ? s[t - off] : 0;
        __syncthreads();
        s[t] += val;
        __syncthreads();
    }
    int run = blockoff_s + ((t == 0) ? 0 : s[t - 1]);
    #pragma unroll
    for (int j = 0; j < 8; ++j) {
        int i = base + j;
        if (i < N) {
            rowptr[i] = run;
            cursor[i] = run;
            inv[i] = 1.0f / (float)max(v[j], 1);
            run += v[j];
        }
    }
    if ((int)blockIdx.x == (int)gridDim.x - 1 && t == 255) rowptr[N] = run;
}

__global__ void fill_csr_kernel(const int* __restrict__ src, const int* __restrict__ dst,
                                int* __restrict__ cursor, int* __restrict__ col, int E) {
    int e = blockIdx.x * 256 + threadIdx.x;
    if (e >= E) return;
    int pos = atomicAdd(&cursor[dst[e]], 1);
    col[pos] = src[e];
}

// 16-feat mean aggregate over fp32 x
__global__ __launch_bounds__(256) void aggregate16_kernel(
    const float* __restrict__ x, const int* __restrict__ rowptr,
    const int* __restrict__ col, const float* __restrict__ inv,
    float* __restrict__ agg, int N) {
    const int t = threadIdx.x;
    const int node = blockIdx.x * 16 + (t >> 4);
    const int f = t & 15;
    if (node >= N) return;
    const int lo = rowptr[node], hi = rowptr[node + 1];
    float acc = 0.0f;
    for (int e = lo; e < hi; ++e)
        acc += x[col[e] * 16 + f];
    agg[node * 16 + f] = acc * inv[node];
}

// 128-feat mean aggregate over bf16 h: wave per node, 2 bf16 (4B) per lane
__global__ __launch_bounds__(256) void aggregate128_kernel(
    const bf16_t* __restrict__ h, const int* __restrict__ rowptr,
    const int* __restrict__ col, const float* __restrict__ inv,
    float* __restrict__ agg, int N) {
    const int t = threadIdx.x;
    const int node = blockIdx.x * 4 + (t >> 6);
    const int lane = t & 63;
    if (node >= N) return;
    const int lo = rowptr[node], hi = rowptr[node + 1];
    float ax = 0.0f, ay = 0.0f;
    int e = lo;
    for (; e + 1 < hi; e += 2) {
        int s0 = col[e], s1 = col[e + 1];
        uint32 v0 = *(const uint32*)&h[(size_t)s0 * 128 + lane * 2];
        uint32 v1 = *(const uint32*)&h[(size_t)s1 * 128 + lane * 2];
        ax += bf2f((bf16_t)(v0 & 0xffff)) + bf2f((bf16_t)(v1 & 0xffff));
        ay += bf2f((bf16_t)(v0 >> 16))    + bf2f((bf16_t)(v1 >> 16));
    }
    if (e < hi) {
        uint32 v0 = *(const uint32*)&h[(size_t)col[e] * 128 + lane * 2];
        ax += bf2f((bf16_t)(v0 & 0xffff));
        ay += bf2f((bf16_t)(v0 >> 16));
    }
    float iv = inv[node];
    *(float2*)&agg[(size_t)node * 128 + lane * 2] = make_float2(ax * iv, ay * iv);
}

// layer 1: 16 -> 128, writes bf16 h
__global__ __launch_bounds__(256) void layer16_kernel(
    const float* __restrict__ agg16, const float* __restrict__ x,
    const float* __restrict__ Wl, const float* __restrict__ Wr,
    const float* __restrict__ bias, bf16_t* __restrict__ hout, int n) {
    const int t = threadIdx.x;
    const int o = t & 127;
    const int node = blockIdx.x * 2 + (t >> 7);
    if (node >= n) return;
    const float* wlr = Wl + o * 16;
    const float* wrr = Wr + o * 16;
    const float* ar = agg16 + node * 16;
    const float* xr = x + node * 16;
    float acc = bias[o];
    #pragma unroll
    for (int f = 0; f < 16; ++f) {
        acc = fmaf(ar[f], wlr[f], acc);
        acc = fmaf(xr[f], wrr[f], acc);
    }
    hout[node * 128 + o] = f2bf(fmaxf(acc, 0.0f));
}

// layer 2/3: 128 -> 128. Block tile 64 nodes x 128 outs; thread tile 8n x 4o.
// Thread outputs are {o0, o0+32, o0+64, o0+96}, o0 = t&31: w-reads have
// lane-stride-1 rows (row stride 36 = 4 mod 32 banks -> conflict-free).
// a_s/h_s unpadded [64][32]: compute reads are wave broadcasts, staging
// writes 2-way (free). LDS total 52KB -> 3 blocks/CU.
__global__ __launch_bounds__(256) void layer128_kernel(
    const float* __restrict__ agg, const bf16_t* __restrict__ hin,
    const float* __restrict__ Wl, const float* __restrict__ Wr,
    const float* __restrict__ bias, bf16_t* __restrict__ hout, int n) {
    __shared__ float wl_s[128][36];
    __shared__ float wr_s[128][36];
    __shared__ float a_s[64][32];
    __shared__ float h_s[64][32];

    const int t = threadIdx.x;
    const int n0 = blockIdx.x * 64;
    const int o0 = t & 31;             // outputs o0 + 32j
    const int nd0 = (t >> 5) * 8;      // 8 consecutive nodes

    float acc[8][4];
    #pragma unroll
    for (int i = 0; i < 8; ++i)
        #pragma unroll
        for (int j = 0; j < 4; ++j) acc[i][j] = 0.0f;

    for (int f0 = 0; f0 < 128; f0 += 32) {
        // stage W chunk: 128 o x 32 k
        #pragma unroll
        for (int j = 0; j < 4; ++j) {
            int q = t + 256 * j;
            int oo = q >> 3, kk = (q & 7) * 4;
            *(float4*)&wl_s[oo][kk] = *(const float4*)&Wl[oo * 128 + f0 + kk];
            *(float4*)&wr_s[oo][kk] = *(const float4*)&Wr[oo * 128 + f0 + kk];
        }
        // stage features: 64 nodes x 32 k; agg fp32 (2 float4), h bf16 (1 uint4)
        {
            int nd = t >> 2;
            int kb = (t & 3) * 8;
            int node = n0 + nd;
            float4 a0 = make_float4(0.f, 0.f, 0.f, 0.f);
            float4 a1 = make_float4(0.f, 0.f, 0.f, 0.f);
            float4 h0 = make_float4(0.f, 0.f, 0.f, 0.f);
            float4 h1 = make_float4(0.f, 0.f, 0.f, 0.f);
            if (node < n) {
                a0 = *(const float4*)&agg[(size_t)node * 128 + f0 + kb];
                a1 = *(const float4*)&agg[(size_t)node * 128 + f0 + kb + 4];
                uint4 hv = *(const uint4*)&hin[(size_t)node * 128 + f0 + kb];
                h0.x = bf2f((bf16_t)(hv.x & 0xffff)); h0.y = bf2f((bf16_t)(hv.x >> 16));
                h0.z = bf2f((bf16_t)(hv.y & 0xffff)); h0.w = bf2f((bf16_t)(hv.y >> 16));
                h1.x = bf2f((bf16_t)(hv.z & 0xffff)); h1.y = bf2f((bf16_t)(hv.z >> 16));
                h1.z = bf2f((bf16_t)(hv.w & 0xffff)); h1.w = bf2f((bf16_t)(hv.w >> 16));
            }
            *(float4*)&a_s[nd][kb]     = a0;
            *(float4*)&a_s[nd][kb + 4] = a1;
            *(float4*)&h_s[nd][kb]     = h0;
            *(float4*)&h_s[nd][kb + 4] = h1;
        }
        __syncthreads();

        #pragma unroll
        for (int k4 = 0; k4 < 32; k4 += 4) {
            float4 wl[4], wr[4];
            #pragma unroll
            for (int j = 0; j < 4; ++j) {
                wl[j] = *(float4*)&wl_s[o0 + 32 * j][k4];
                wr[j] = *(float4*)&wr_s[o0 + 32 * j][k4];
            }
            #pragma unroll
            for (int i = 0; i < 8; ++i) {
                float4 va = *(float4*)&a_s[nd0 + i][k4];
                float4 vh = *(float4*)&h_s[nd0 + i][k4];
                #pragma unroll
                for (int j = 0; j < 4; ++j) {
                    acc[i][j] = fmaf(va.x, wl[j].x, fmaf(va.y, wl[j].y,
                                fmaf(va.z, wl[j].z, fmaf(va.w, wl[j].w, acc[i][j]))));
                    acc[i][j] = fmaf(vh.x, wr[j].x, fmaf(vh.y, wr[j].y,
                                fmaf(vh.z, wr[j].z, fmaf(vh.w, wr[j].w, acc[i][j]))));
                }
            }
        }
        __syncthreads();
    }

    #pragma unroll
    for (int j = 0; j < 4; ++j) {
        int o = o0 + 32 * j;
        float bo = bias[o];
        #pragma unroll
        for (int i = 0; i < 8; ++i) {
            int node = n0 + nd0 + i;
            if (node < n)
                hout[(size_t)node * 128 + o] = f2bf(fmaxf(acc[i][j] + bo, 0.0f));
        }
    }
}

// head: 128 -> 4 from bf16 h (no relu)
__global__ void head_kernel(const bf16_t* __restrict__ h,
                            const float* __restrict__ Wh,
                            const float* __restrict__ bh,
                            float* __restrict__ out, int n) {
    int idx = blockIdx.x * 256 + threadIdx.x;
    if (idx >= n * 4) return;
    int node = idx >> 2;
    int o = idx & 3;
    const bf16_t* hr = h + (size_t)node * 128;
    const float* wr = Wh + o * 128;
    float acc = bh[o];
    #pragma unroll 4
    for (int f = 0; f < 128; f += 4) {
        acc = fmaf(bf2f(hr[f + 0]), wr[f + 0], acc);
        acc = fmaf(bf2f(hr[f + 1]), wr[f + 1], acc);
        acc = fmaf(bf2f(hr[f + 2]), wr[f + 2], acc);
        acc = fmaf(bf2f(hr[f + 3]), wr[f + 3], acc);
    }
    out[idx] = acc;
}

extern "C" void kernel_launch(void* const* d_in, const int* in_sizes, int n_in,
                              void* d_out, int out_size, void* d_ws, size_t ws_size,
                              hipStream_t stream) {
    const float* x   = (const float*)d_in[0];
    const int*   ei  = (const int*)d_in[1];
    const float* Wl1 = (const float*)d_in[2];
    const float* Wr1 = (const float*)d_in[3];
    const float* b1  = (const float*)d_in[4];
    const float* Wl2 = (const float*)d_in[5];
    const float* Wr2 = (const float*)d_in[6];
    const float* b2  = (const float*)d_in[7];
    const float* Wl3 = (const float*)d_in[8];
    const float* Wr3 = (const float*)d_in[9];
    const float* b3  = (const float*)d_in[10];
    const float* Wh  = (const float*)d_in[11];
    const float* bh  = (const float*)d_in[12];
    float* out = (float*)d_out;

    const int N = in_sizes[0] / 16;
    const int E = in_sizes[1] / 2;
    const int* src = ei;
    const int* dst = ei + E;

    const int nScanBlocks = (N + SCAN_CHUNK - 1) / SCAN_CHUNK;

    int* deg      = (int*)d_ws;                   // N
    int* rowptr   = deg + N;                      // N+1 (pad 8)
    int* cursor   = rowptr + (N + 8);             // N
    int* blocksum = cursor + N;                   // pad 64
    int* col      = blocksum + 64;                // E
    float* inv    = (float*)(col + E);            // N
    float* agg    = inv + N;                      // N*128 fp32
    bf16_t* hA    = (bf16_t*)(agg + (size_t)N * 128); // N*128 bf16
    bf16_t* hB    = hA + (size_t)N * 128;             // N*128 bf16

    const int B = 256;
    auto blocks = [](long total, int b) { return (int)((total + b - 1) / b); };

    // ---- CSR build ----
    zero_int_kernel<<<blocks(N, B), B, 0, stream>>>(deg, N);
    count_deg_kernel<<<blocks(E, B), B, 0, stream>>>(dst, deg, E);
    scan_partial_kernel<<<nScanBlocks, B, 0, stream>>>(deg, blocksum, N);
    scan_final_kernel<<<nScanBlocks, B, 0, stream>>>(deg, blocksum, rowptr, cursor, inv, N);
    fill_csr_kernel<<<blocks(E, B), B, 0, stream>>>(src, dst, cursor, col, E);

    // ---- layer 1: 16 -> 128 ----
    aggregate16_kernel<<<blocks(N, 16), B, 0, stream>>>(x, rowptr, col, inv, agg, N);
    layer16_kernel<<<blocks(N, 2), B, 0, stream>>>(agg, x, Wl1, Wr1, b1, hA, N);

    // ---- layer 2: 128 -> 128 ----
    aggregate128_kernel<<<blocks(N, 4), B, 0, stream>>>(hA, rowptr, col, inv, agg, N);
    layer128_kernel<<<blocks(N, 64), B, 0, stream>>>(agg, hA, Wl2, Wr2, b2, hB, N);

    // ---- layer 3: 128 -> 128 ----
    aggregate128_kernel<<<blocks(N, 4), B, 0, stream>>>(hB, rowptr, col, inv, agg, N);
    layer128_kernel<<<blocks(N, 64), B, 0, stream>>>(agg, hB, Wl3, Wr3, b3, hA, N);

    // ---- head: 128 -> 4 ----
    head_kernel<<<blocks((long)N * 4, B), B, 0, stream>>>(hA, Wh, bh, out, N);
}

// Round 5
// 397.208 us; speedup vs baseline: 3.6222x; 1.2099x over previous
//
#include <hip/hip_runtime.h>
#include <hip/hip_bf16.h>

// ---------------------------------------------------------------------------
// GraphSAGE (3x SAGEConv mean + linear head), CSR gather formulation.
// Hidden activations AND aggregated means stored as bf16; layers 2/3 run as
// MFMA bf16 GEMM: out = [agg|h] @ [Wl|Wr]^T, K=256, fragments loaded
// straight from global (A: activation rows, B: bf16-converted weight rows,
// L1/L2-resident). No LDS, no barriers in the GEMM.
// ---------------------------------------------------------------------------

#define SCAN_CHUNK 2048

typedef unsigned short bf16_t;
typedef unsigned int uint32;
typedef __attribute__((ext_vector_type(8))) short bf16x8;   // 8 bf16 = 4 VGPRs
typedef __attribute__((ext_vector_type(4))) float f32x4;

__device__ __forceinline__ bf16_t f2bf(float f) {
    uint32 u = __float_as_uint(f);
    u += 0x7fff + ((u >> 16) & 1);           // round-to-nearest-even
    return (bf16_t)(u >> 16);
}
__device__ __forceinline__ float bf2f(bf16_t b) {
    return __uint_as_float((uint32)b << 16);
}

__global__ void zero_int_kernel(int* __restrict__ p, int n) {
    int i = blockIdx.x * 256 + threadIdx.x;
    if (i < n) p[i] = 0;
}

__global__ void count_deg_kernel(const int* __restrict__ dst, int* __restrict__ deg, int E) {
    int e = blockIdx.x * 256 + threadIdx.x;
    if (e < E) atomicAdd(&deg[dst[e]], 1);
}

__global__ __launch_bounds__(256) void scan_partial_kernel(
    const int* __restrict__ deg, int* __restrict__ blocksum, int N) {
    __shared__ int s[256];
    const int t = threadIdx.x;
    const int base = blockIdx.x * SCAN_CHUNK + t * 8;
    int sum = 0;
    #pragma unroll
    for (int j = 0; j < 8; ++j) {
        int i = base + j;
        if (i < N) sum += deg[i];
    }
    s[t] = sum;
    __syncthreads();
    #pragma unroll
    for (int off = 128; off > 0; off >>= 1) {
        if (t < off) s[t] += s[t + off];
        __syncthreads();
    }
    if (t == 0) blocksum[blockIdx.x] = s[0];
}

__global__ __launch_bounds__(256) void scan_final_kernel(
    const int* __restrict__ deg, const int* __restrict__ blocksum,
    int* __restrict__ rowptr, int* __restrict__ cursor,
    float* __restrict__ inv, int N) {
    __shared__ int s[256];
    __shared__ int blockoff_s;
    const int t = threadIdx.x;
    if (t == 0) {
        int off = 0;
        for (int b = 0; b < (int)blockIdx.x; ++b) off += blocksum[b];
        blockoff_s = off;
    }
    const int base = blockIdx.x * SCAN_CHUNK + t * 8;
    int v[8];
    int sum = 0;
    #pragma unroll
    for (int j = 0; j < 8; ++j) {
        int i = base + j;
        v[j] = (i < N) ? deg[i] : 0;
        sum += v[j];
    }
    s[t] = sum;
    __syncthreads();
    for (int off = 1; off < 256; off <<= 1) {
        int val = (t >= off) ? s[t - off] : 0;
        __syncthreads();
        s[t] += val;
        __syncthreads();
    }
    int run = blockoff_s + ((t == 0) ? 0 : s[t - 1]);
    #pragma unroll
    for (int j = 0; j < 8; ++j) {
        int i = base + j;
        if (i < N) {
            rowptr[i] = run;
            cursor[i] = run;
            inv[i] = 1.0f / (float)max(v[j], 1);
            run += v[j];
        }
    }
    if ((int)blockIdx.x == (int)gridDim.x - 1 && t == 255) rowptr[N] = run;
}

__global__ void fill_csr_kernel(const int* __restrict__ src, const int* __restrict__ dst,
                                int* __restrict__ cursor, int* __restrict__ col, int E) {
    int e = blockIdx.x * 256 + threadIdx.x;
    if (e >= E) return;
    int pos = atomicAdd(&cursor[dst[e]], 1);
    col[pos] = src[e];
}

// combine Wl|Wr (fp32, [128][128] each) -> wbf [128 o][256 k] bf16
__global__ void convert_w_kernel(const float* __restrict__ Wl, const float* __restrict__ Wr,
                                 bf16_t* __restrict__ wbf) {
    int idx = blockIdx.x * 256 + threadIdx.x;   // 0..32767
    int o = idx >> 8;
    int k = idx & 255;
    float v = (k < 128) ? Wl[o * 128 + k] : Wr[o * 128 + k - 128];
    wbf[idx] = f2bf(v);
}

// 16-feat mean aggregate over fp32 x -> fp32 agg16
__global__ __launch_bounds__(256) void aggregate16_kernel(
    const float* __restrict__ x, const int* __restrict__ rowptr,
    const int* __restrict__ col, const float* __restrict__ inv,
    float* __restrict__ agg, int N) {
    const int t = threadIdx.x;
    const int node = blockIdx.x * 16 + (t >> 4);
    const int f = t & 15;
    if (node >= N) return;
    const int lo = rowptr[node], hi = rowptr[node + 1];
    float acc = 0.0f;
    for (int e = lo; e < hi; ++e)
        acc += x[col[e] * 16 + f];
    agg[node * 16 + f] = acc * inv[node];
}

// 128-feat mean aggregate over bf16 h -> bf16 agg: wave per node, 4B per lane
__global__ __launch_bounds__(256) void aggregate128_kernel(
    const bf16_t* __restrict__ h, const int* __restrict__ rowptr,
    const int* __restrict__ col, const float* __restrict__ inv,
    bf16_t* __restrict__ aggb, int N) {
    const int t = threadIdx.x;
    const int node = blockIdx.x * 4 + (t >> 6);
    const int lane = t & 63;
    if (node >= N) return;
    const int lo = rowptr[node], hi = rowptr[node + 1];
    float ax = 0.0f, ay = 0.0f;
    int e = lo;
    for (; e + 1 < hi; e += 2) {
        int s0 = col[e], s1 = col[e + 1];
        uint32 v0 = *(const uint32*)&h[(size_t)s0 * 128 + lane * 2];
        uint32 v1 = *(const uint32*)&h[(size_t)s1 * 128 + lane * 2];
        ax += bf2f((bf16_t)(v0 & 0xffff)) + bf2f((bf16_t)(v1 & 0xffff));
        ay += bf2f((bf16_t)(v0 >> 16))    + bf2f((bf16_t)(v1 >> 16));
    }
    if (e < hi) {
        uint32 v0 = *(const uint32*)&h[(size_t)col[e] * 128 + lane * 2];
        ax += bf2f((bf16_t)(v0 & 0xffff));
        ay += bf2f((bf16_t)(v0 >> 16));
    }
    float iv = inv[node];
    uint32 packed = (uint32)f2bf(ax * iv) | ((uint32)f2bf(ay * iv) << 16);
    *(uint32*)&aggb[(size_t)node * 128 + lane * 2] = packed;
}

// layer 1: 16 -> 128, fp32 in, bf16 h out
__global__ __launch_bounds__(256) void layer16_kernel(
    const float* __restrict__ agg16, const float* __restrict__ x,
    const float* __restrict__ Wl, const float* __restrict__ Wr,
    const float* __restrict__ bias, bf16_t* __restrict__ hout, int n) {
    const int t = threadIdx.x;
    const int o = t & 127;
    const int node = blockIdx.x * 2 + (t >> 7);
    if (node >= n) return;
    const float* wlr = Wl + o * 16;
    const float* wrr = Wr + o * 16;
    const float* ar = agg16 + node * 16;
    const float* xr = x + node * 16;
    float acc = bias[o];
    #pragma unroll
    for (int f = 0; f < 16; ++f) {
        acc = fmaf(ar[f], wlr[f], acc);
        acc = fmaf(xr[f], wrr[f], acc);
    }
    hout[node * 128 + o] = f2bf(fmaxf(acc, 0.0f));
}

// layers 2/3 as MFMA bf16 GEMM. out[m,o] = relu(b[o] + sum_k A[m,k] W[o,k]),
// A = [agg | h] (K=256). Wave tile: M=32 (2 m-tiles), N=64 (4 n-tiles).
// A-frag: lane holds A[m0+(lane&15)][quad*8 + j] (16B contiguous load).
// B-frag: lane holds W[n0+(lane&15)][quad*8 + j] (16B contiguous, L1/L2-hit).
// C/D: col = lane&15, row = quad*4 + reg (m89-verified). No LDS, no barriers.
__global__ __launch_bounds__(256) void layer128_mfma_kernel(
    const bf16_t* __restrict__ aggb, const bf16_t* __restrict__ hin,
    const bf16_t* __restrict__ wbf, const float* __restrict__ bias,
    bf16_t* __restrict__ hout, int n) {
    const int t = threadIdx.x;
    const int lane = t & 63;
    const int wave = t >> 6;
    const int r = lane & 15;
    const int q = lane >> 4;
    const int m0 = blockIdx.x * 64 + (wave >> 1) * 32;   // 32 nodes per wave
    const int nb = (wave & 1) * 64;                      // 64 outs per wave

    // A fragments: 2 m-tiles x 8 k-steps, held in registers (64 VGPRs)
    bf16x8 aF[2][8];
    #pragma unroll
    for (int mt = 0; mt < 2; ++mt) {
        int node = m0 + mt * 16 + r;
        if (node >= n) node = n - 1;                 // clamp; stores predicated
        const bf16_t* arow = aggb + (size_t)node * 128;
        const bf16_t* hrow = hin + (size_t)node * 128;
        #pragma unroll
        for (int ks = 0; ks < 4; ++ks)
            aF[mt][ks] = *(const bf16x8*)(arow + ks * 32 + q * 8);
        #pragma unroll
        for (int ks = 0; ks < 4; ++ks)
            aF[mt][4 + ks] = *(const bf16x8*)(hrow + ks * 32 + q * 8);
    }

    #pragma unroll
    for (int nt = 0; nt < 4; ++nt) {
        const int col = nb + nt * 16 + r;
        const bf16_t* wrow = wbf + (size_t)col * 256;
        f32x4 acc0 = {0.f, 0.f, 0.f, 0.f};
        f32x4 acc1 = {0.f, 0.f, 0.f, 0.f};
        #pragma unroll
        for (int ks = 0; ks < 8; ++ks) {
            bf16x8 bF = *(const bf16x8*)(wrow + ks * 32 + q * 8);
            acc0 = __builtin_amdgcn_mfma_f32_16x16x32_bf16(aF[0][ks], bF, acc0, 0, 0, 0);
            acc1 = __builtin_amdgcn_mfma_f32_16x16x32_bf16(aF[1][ks], bF, acc1, 0, 0, 0);
        }
        float bo = bias[col];
        #pragma unroll
        for (int reg = 0; reg < 4; ++reg) {
            int row0 = m0 + q * 4 + reg;
            if (row0 < n)
                hout[(size_t)row0 * 128 + col] = f2bf(fmaxf(acc0[reg] + bo, 0.0f));
            int row1 = m0 + 16 + q * 4 + reg;
            if (row1 < n)
                hout[(size_t)row1 * 128 + col] = f2bf(fmaxf(acc1[reg] + bo, 0.0f));
        }
    }
}

// head: 128 -> 4 from bf16 h (no relu)
__global__ void head_kernel(const bf16_t* __restrict__ h,
                            const float* __restrict__ Wh,
                            const float* __restrict__ bh,
                            float* __restrict__ out, int n) {
    int idx = blockIdx.x * 256 + threadIdx.x;
    if (idx >= n * 4) return;
    int node = idx >> 2;
    int o = idx & 3;
    const bf16_t* hr = h + (size_t)node * 128;
    const float* wr = Wh + o * 128;
    float acc = bh[o];
    #pragma unroll 4
    for (int f = 0; f < 128; f += 4) {
        acc = fmaf(bf2f(hr[f + 0]), wr[f + 0], acc);
        acc = fmaf(bf2f(hr[f + 1]), wr[f + 1], acc);
        acc = fmaf(bf2f(hr[f + 2]), wr[f + 2], acc);
        acc = fmaf(bf2f(hr[f + 3]), wr[f + 3], acc);
    }
    out[idx] = acc;
}

extern "C" void kernel_launch(void* const* d_in, const int* in_sizes, int n_in,
                              void* d_out, int out_size, void* d_ws, size_t ws_size,
                              hipStream_t stream) {
    const float* x   = (const float*)d_in[0];
    const int*   ei  = (const int*)d_in[1];
    const float* Wl1 = (const float*)d_in[2];
    const float* Wr1 = (const float*)d_in[3];
    const float* b1  = (const float*)d_in[4];
    const float* Wl2 = (const float*)d_in[5];
    const float* Wr2 = (const float*)d_in[6];
    const float* b2  = (const float*)d_in[7];
    const float* Wl3 = (const float*)d_in[8];
    const float* Wr3 = (const float*)d_in[9];
    const float* b3  = (const float*)d_in[10];
    const float* Wh  = (const float*)d_in[11];
    const float* bh  = (const float*)d_in[12];
    float* out = (float*)d_out;

    const int N = in_sizes[0] / 16;
    const int E = in_sizes[1] / 2;
    const int* src = ei;
    const int* dst = ei + E;

    const int nScanBlocks = (N + SCAN_CHUNK - 1) / SCAN_CHUNK;

    int* deg       = (int*)d_ws;                       // N
    int* rowptr    = deg + N;                          // N+1 (pad 8)
    int* cursor    = rowptr + (N + 8);                 // N
    int* blocksum  = cursor + N;                       // pad 64
    int* col       = blocksum + 64;                    // E
    float* inv     = (float*)(col + E);                // N
    float* agg16f  = inv + N;                          // N*16 fp32
    bf16_t* aggb   = (bf16_t*)(agg16f + (size_t)N * 16); // N*128 bf16
    bf16_t* hA     = aggb + (size_t)N * 128;           // N*128 bf16
    bf16_t* hB     = hA + (size_t)N * 128;             // N*128 bf16
    bf16_t* wbf2   = hB + (size_t)N * 128;             // 128*256 bf16
    bf16_t* wbf3   = wbf2 + 128 * 256;                 // 128*256 bf16

    const int B = 256;
    auto blocks = [](long total, int b) { return (int)((total + b - 1) / b); };

    // ---- CSR build + weight conversion (independent, early) ----
    zero_int_kernel<<<blocks(N, B), B, 0, stream>>>(deg, N);
    count_deg_kernel<<<blocks(E, B), B, 0, stream>>>(dst, deg, E);
    convert_w_kernel<<<128, B, 0, stream>>>(Wl2, Wr2, wbf2);
    convert_w_kernel<<<128, B, 0, stream>>>(Wl3, Wr3, wbf3);
    scan_partial_kernel<<<nScanBlocks, B, 0, stream>>>(deg, blocksum, N);
    scan_final_kernel<<<nScanBlocks, B, 0, stream>>>(deg, blocksum, rowptr, cursor, inv, N);
    fill_csr_kernel<<<blocks(E, B), B, 0, stream>>>(src, dst, cursor, col, E);

    // ---- layer 1: 16 -> 128 ----
    aggregate16_kernel<<<blocks(N, 16), B, 0, stream>>>(x, rowptr, col, inv, agg16f, N);
    layer16_kernel<<<blocks(N, 2), B, 0, stream>>>(agg16f, x, Wl1, Wr1, b1, hA, N);

    // ---- layer 2: 128 -> 128 (MFMA) ----
    aggregate128_kernel<<<blocks(N, 4), B, 0, stream>>>(hA, rowptr, col, inv, aggb, N);
    layer128_mfma_kernel<<<blocks(N, 64), B, 0, stream>>>(aggb, hA, wbf2, b2, hB, N);

    // ---- layer 3: 128 -> 128 (MFMA) ----
    aggregate128_kernel<<<blocks(N, 4), B, 0, stream>>>(hB, rowptr, col, inv, aggb, N);
    layer128_mfma_kernel<<<blocks(N, 64), B, 0, stream>>>(aggb, hB, wbf3, b3, hA, N);

    // ---- head: 128 -> 4 ----
    head_kernel<<<blocks((long)N * 4, B), B, 0, stream>>>(hA, Wh, bh, out, N);
}